// Round 1
// baseline (124.362 us; speedup 1.0000x reference)
//
#include <hip/hip_runtime.h>
#include <hip/hip_bf16.h>
#include <stdint.h>

typedef __attribute__((ext_vector_type(8))) short short8;
typedef __attribute__((ext_vector_type(8))) __bf16 bf16x8;
typedef __attribute__((ext_vector_type(4))) float f32x4;
typedef __attribute__((ext_vector_type(4))) unsigned short us4;
typedef unsigned int u32;
typedef __attribute__((address_space(3))) u32 lds_u32;
typedef const __attribute__((address_space(1))) u32 g_u32;

#define NSEQ 2048
#define L2E 1.44269504088896f

static __device__ __forceinline__ unsigned short f2bf(float x){
  union { float f; u32 u; } v; v.f = x;
  u32 r = v.u + 0x7fffu + ((v.u >> 16) & 1u);
  return (unsigned short)(r >> 16);
}
static __device__ __forceinline__ float bf2f(unsigned short s){
  union { float f; u32 u; } v; v.u = ((u32)s) << 16; return v.f;
}
static __device__ __forceinline__ void gload16(const void* g, void* l){
  __builtin_amdgcn_global_load_lds((g_u32*)g, (lds_u32*)l, 16, 0, 0);
}
static __device__ __forceinline__ f32x4 mfma16(bf16x8 a, bf16x8 b, f32x4 c){
  return __builtin_amdgcn_mfma_f32_16x16x32_bf16(a, b, c, 0, 0, 0);
}
static __device__ __forceinline__ bf16x8 ldfrag(const void* p){
  return *(const bf16x8*)p;
}

// ---------------- kernel 1: convert inputs to bf16, transpose weights ----------------
__global__ void cvt_kernel(const float* __restrict__ qx, const float* __restrict__ kvx,
                           const float* __restrict__ Wq, const float* __restrict__ Wk,
                           const float* __restrict__ Wv, const float* __restrict__ Wg,
                           const float* __restrict__ Wo,
                           unsigned short* __restrict__ Xbq, unsigned short* __restrict__ Xbkv,
                           unsigned short* __restrict__ Wt4, unsigned short* __restrict__ Wot){
  int stride = gridDim.x * blockDim.x;
  int tid = blockIdx.x * blockDim.x + threadIdx.x;
  for (int i = tid; i < NSEQ*256; i += stride){
    Xbq[i]  = f2bf(qx[i]);
    Xbkv[i] = f2bf(kvx[i]);
  }
  // weight transposes: Wt[o][i] = W[i][o]  (B^T form for the MFMA GEMMs)
  for (int j = tid; j < 5*65536; j += stride){
    int w = j >> 16, idx = j & 65535, o = idx >> 8, i = idx & 255;
    const float* W = (w==0)?Wq:((w==1)?Wk:((w==2)?Wv:((w==3)?Wg:Wo)));
    float v = W[i*256 + o];
    if (w == 0) v *= 0.17677669529663687f;  // fold 1/sqrt(32) into Wq
    if (w < 4) Wt4[w*65536 + o*256 + i] = f2bf(v);
    else       Wot[o*256 + i] = f2bf(v);
  }
}

// ---------------- kernel 2: fused QKVG projection GEMM ----------------
// C[2048, 1024] = X @ [Wq|Wk|Wv|Wg], tile 64x64, K=256 fully staged.
__global__ __launch_bounds__(256) void proj_kernel(const unsigned short* __restrict__ Xbq,
     const unsigned short* __restrict__ Xbkv, const unsigned short* __restrict__ Wt4,
     unsigned short* __restrict__ Qb, unsigned short* __restrict__ Kb,
     unsigned short* __restrict__ Vt, unsigned short* __restrict__ Gg){
  __shared__ unsigned short Asm[64*256];
  __shared__ unsigned short Bsm[64*256];
  int mt = blockIdx.x;            // 0..31
  int nt = blockIdx.y;            // 0..15
  int col0 = nt * 64;
  int w = col0 >> 8;              // which weight: 0=Q 1=K 2=V 3=G
  const unsigned short* A = (w==0 || w==3) ? Xbq : Xbkv;
  int tid = threadIdx.x, lane = tid & 63, wid = tid >> 6;
  const char* Ab = (const char*)A   + (size_t)mt*64*512;
  const char* Bb = (const char*)Wt4 + (size_t)col0*512;
  char* Asl = (char*)Asm; char* Bsl = (char*)Bsm;
  // stage both 32KB tiles; rows are 512B; XOR-swizzle f(row)=(row&15)<<4 applied
  // on the GLOBAL source so LDS dest stays linear (global_load_lds constraint).
  #pragma unroll
  for (int it = 0; it < 8; ++it){
    int o = it*4096 + wid*1024 + lane*16;
    int row = o >> 9, b = o & 511;
    int sb = (o & ~511) + (b ^ ((row & 15) << 4));
    gload16(Ab + sb, Asl + it*4096 + wid*1024);
    gload16(Bb + sb, Bsl + it*4096 + wid*1024);
  }
  __syncthreads();
  int ml = lane & 15, kg = lane >> 4;
  int m = wid*16 + ml;
  bf16x8 afr[8];
  #pragma unroll
  for (int ks = 0; ks < 8; ++ks)
    afr[ks] = ldfrag(Asl + m*512 + ((ks*64 + kg*16) ^ (ml << 4)));
  f32x4 acc[4];
  #pragma unroll
  for (int ct = 0; ct < 4; ++ct){
    acc[ct] = (f32x4){0.f,0.f,0.f,0.f};
    int oo = ct*16 + ml;
    #pragma unroll
    for (int ks = 0; ks < 8; ++ks){
      bf16x8 bfr = ldfrag(Bsl + oo*512 + ((ks*64 + kg*16) ^ (ml << 4)));
      acc[ct] = mfma16(afr[ks], bfr, acc[ct]);
    }
  }
  // epilogue: scatter to per-use layouts
  #pragma unroll
  for (int ct = 0; ct < 4; ++ct){
    int colg = col0 + ct*16 + ml;
    int cw = colg & 255, hh = cw >> 5, c = cw & 31;
    int n0 = mt*64 + wid*16 + kg*4;
    if (w == 2){
      // V stored transposed [h][c][n]; 4 consecutive n pack into one 8B store
      us4 pk;
      pk[0]=f2bf(acc[ct][0]); pk[1]=f2bf(acc[ct][1]);
      pk[2]=f2bf(acc[ct][2]); pk[3]=f2bf(acc[ct][3]);
      *(us4*)((char*)Vt + ((size_t)(hh*32 + c)*NSEQ + n0)*2) = pk;
    } else {
      #pragma unroll
      for (int r = 0; r < 4; ++r){
        int n = n0 + r;
        float v = acc[ct][r];
        if (w == 0)      Qb[((size_t)hh*NSEQ + n)*32 + c] = f2bf(v);
        else if (w == 1) Kb[((size_t)hh*NSEQ + n)*32 + c] = f2bf(v);
        else             Gg[(size_t)n*256 + cw] = f2bf(1.f/(1.f + __expf(-v)));
      }
    }
  }
}

// ---------------- kernel 3: fused bias-attention (flash-style) ----------------
// grid 256: one block per (head, 64-row q tile). 4 waves, each owns 16 q rows.
// S acc is INITIALIZED with bias regs (loaded in C-layout) -> bias read = acc init.
__global__ __launch_bounds__(256) void attn_kernel(const unsigned short* __restrict__ Qb,
    const unsigned short* __restrict__ Kb, const unsigned short* __restrict__ Vt,
    const unsigned short* __restrict__ Gg, const float* __restrict__ bias,
    unsigned short* __restrict__ Og){
  __shared__ unsigned short Ksm[2][4096];   // [128 kv rows][32 c] bf16, dbuf
  __shared__ unsigned short Vsm[2][4096];   // [32 c][128 kv] bf16, dbuf
  __shared__ unsigned short Psm[8192];      // [64 q][128 kv] bf16
  int bid = blockIdx.x;
  int h = bid >> 5, qt = bid & 31;
  int q0 = qt * 64;
  int tid = threadIdx.x, lane = tid & 63, wid = tid >> 6;
  int ml = lane & 15, kg = lane >> 4;
  int qw = q0 + wid*16;
  bf16x8 qfr = ldfrag((const char*)Qb + (((size_t)h*NSEQ + qw + ml)*32 + kg*8)*2);
  const char* Kbase = (const char*)Kb + (size_t)h*NSEQ*32*2;
  const char* Vbase = (const char*)Vt + (size_t)h*32*NSEQ*2;
  const float* bias_h = bias + (size_t)h*NSEQ*NSEQ;
  float mreg[4] = {-3e38f,-3e38f,-3e38f,-3e38f};
  float lreg[4] = {0.f,0.f,0.f,0.f};
  f32x4 oacc[2];
  oacc[0] = (f32x4){0.f,0.f,0.f,0.f};
  oacc[1] = (f32x4){0.f,0.f,0.f,0.f};
  f32x4 breg[2][8];

  auto stage = [&](int t, int buf){
    const char* Kt = Kbase + (size_t)t*128*64;   // tile contiguous: 128 rows * 64B
    char* Kl = (char*)&Ksm[buf][0];
    char* Vl = (char*)&Vsm[buf][0];
    #pragma unroll
    for (int it = 0; it < 2; ++it){
      int o = it*4096 + wid*1024 + lane*16;
      int n = o >> 6, b = o & 63;
      gload16(Kt + (o & ~63) + (b ^ ((((n>>1)&3)) << 4)), Kl + it*4096 + wid*1024);
      int c = o >> 8, vb = o & 255;
      gload16(Vbase + (size_t)c*4096 + (size_t)t*256 + (vb ^ ((c&15) << 4)),
              Vl + it*4096 + wid*1024);
    }
  };
  auto bload = [&](int t, f32x4* dst){
    int kt = t*128;
    #pragma unroll
    for (int ct = 0; ct < 8; ++ct){
      #pragma unroll
      for (int r = 0; r < 4; ++r)
        dst[ct][r] = bias_h[(size_t)(qw + kg*4 + r)*NSEQ + kt + ct*16 + ml];
    }
  };

  stage(0, 0);
  bload(0, breg[0]);
  for (int t = 0; t < 16; ++t){
    int cur = t & 1;
    __syncthreads();   // staging(t) + bias(t) drained here (barrier implies vmcnt(0))
    // S = bias + Q K^T   (one 16x16x32 MFMA per 16-col tile: K-dim == c == 32)
    f32x4 s[8];
    #pragma unroll
    for (int ct = 0; ct < 8; ++ct){
      s[ct] = breg[cur][ct];
      int n = ct*16 + ml;
      bf16x8 kfr = ldfrag((char*)&Ksm[cur][0] + n*64 + ((kg*16) ^ (((n>>1)&3) << 4)));
      s[ct] = mfma16(qfr, kfr, s[ct]);
    }
    // prefetch next tile while we do softmax+PV
    if (t < 15){
      stage(t+1, cur^1);
      bload(t+1, breg[cur^1]);
    }
    // online softmax over the wave's 16 rows (row r lives in 16 lanes of a quarter-group)
    float mx[4];
    #pragma unroll
    for (int r = 0; r < 4; ++r){
      mx[r] = s[0][r];
      #pragma unroll
      for (int ct = 1; ct < 8; ++ct) mx[r] = fmaxf(mx[r], s[ct][r]);
    }
    #pragma unroll
    for (int d = 1; d < 16; d <<= 1){
      #pragma unroll
      for (int r = 0; r < 4; ++r) mx[r] = fmaxf(mx[r], __shfl_xor(mx[r], d));
    }
    float sc[4], rs[4];
    #pragma unroll
    for (int r = 0; r < 4; ++r){
      float mn = fmaxf(mreg[r], mx[r]);
      sc[r] = exp2f((mreg[r] - mn) * L2E);
      mreg[r] = mn;
      rs[r] = 0.f;
    }
    #pragma unroll
    for (int ct = 0; ct < 8; ++ct){
      #pragma unroll
      for (int r = 0; r < 4; ++r){
        float pv = exp2f((s[ct][r] - mreg[r]) * L2E);
        s[ct][r] = pv;
        rs[r] += pv;
      }
    }
    #pragma unroll
    for (int d = 1; d < 16; d <<= 1){
      #pragma unroll
      for (int r = 0; r < 4; ++r) rs[r] += __shfl_xor(rs[r], d);
    }
    #pragma unroll
    for (int r = 0; r < 4; ++r) lreg[r] = lreg[r]*sc[r] + rs[r];
    #pragma unroll
    for (int c2 = 0; c2 < 2; ++c2){
      #pragma unroll
      for (int r = 0; r < 4; ++r) oacc[c2][r] *= sc[r];
    }
    // P -> LDS (bf16, XOR-swizzled rows); each wave touches only its own 16 rows
    #pragma unroll
    for (int ct = 0; ct < 8; ++ct){
      #pragma unroll
      for (int r = 0; r < 4; ++r){
        int q = wid*16 + kg*4 + r;
        int k = ct*16 + ml;
        *(unsigned short*)((char*)Psm + q*256 + ((k*2) ^ ((q&15) << 4))) = f2bf(s[ct][r]);
      }
    }
    // O += P V
    int qq = wid*16 + ml;
    #pragma unroll
    for (int ks = 0; ks < 4; ++ks){
      bf16x8 pfr = ldfrag((char*)Psm + qq*256 + ((ks*64 + kg*16) ^ ((qq&15) << 4)));
      #pragma unroll
      for (int c2 = 0; c2 < 2; ++c2){
        int c = c2*16 + ml;
        bf16x8 vfr = ldfrag((char*)&Vsm[cur][0] + c*256 + ((ks*64 + kg*16) ^ ((c&15) << 4)));
        oacc[c2] = mfma16(pfr, vfr, oacc[c2]);
      }
    }
  }
  // epilogue: O/l * gate -> Og bf16 [n][256]
  #pragma unroll
  for (int c2 = 0; c2 < 2; ++c2){
    #pragma unroll
    for (int r = 0; r < 4; ++r){
      int q = qw + kg*4 + r;
      int col = h*32 + c2*16 + ml;
      float g = bf2f(Gg[(size_t)q*256 + col]);
      float v = oacc[c2][r] / lreg[r] * g;
      Og[(size_t)q*256 + col] = f2bf(v);
    }
  }
}

// ---------------- kernel 4: output projection ----------------
__global__ __launch_bounds__(256) void oproj_kernel(const unsigned short* __restrict__ Og,
    const unsigned short* __restrict__ Wot, float* __restrict__ out){
  __shared__ unsigned short Asm[64*256];
  __shared__ unsigned short Bsm[64*256];
  int mt = blockIdx.x, nt = blockIdx.y;
  int col0 = nt * 64;
  int tid = threadIdx.x, lane = tid & 63, wid = tid >> 6;
  const char* Ab = (const char*)Og  + (size_t)mt*64*512;
  const char* Bb = (const char*)Wot + (size_t)col0*512;
  char* Asl = (char*)Asm; char* Bsl = (char*)Bsm;
  #pragma unroll
  for (int it = 0; it < 8; ++it){
    int o = it*4096 + wid*1024 + lane*16;
    int row = o >> 9, b = o & 511;
    int sb = (o & ~511) + (b ^ ((row & 15) << 4));
    gload16(Ab + sb, Asl + it*4096 + wid*1024);
    gload16(Bb + sb, Bsl + it*4096 + wid*1024);
  }
  __syncthreads();
  int ml = lane & 15, kg = lane >> 4;
  int m = wid*16 + ml;
  bf16x8 afr[8];
  #pragma unroll
  for (int ks = 0; ks < 8; ++ks)
    afr[ks] = ldfrag(Asl + m*512 + ((ks*64 + kg*16) ^ (ml << 4)));
  f32x4 acc[4];
  #pragma unroll
  for (int ct = 0; ct < 4; ++ct){
    acc[ct] = (f32x4){0.f,0.f,0.f,0.f};
    int oo = ct*16 + ml;
    #pragma unroll
    for (int ks = 0; ks < 8; ++ks){
      bf16x8 bfr = ldfrag(Bsl + oo*512 + ((ks*64 + kg*16) ^ (ml << 4)));
      acc[ct] = mfma16(afr[ks], bfr, acc[ct]);
    }
  }
  #pragma unroll
  for (int ct = 0; ct < 4; ++ct){
    #pragma unroll
    for (int r = 0; r < 4; ++r){
      int mm = mt*64 + wid*16 + kg*4 + r;
      out[(size_t)mm*256 + col0 + ct*16 + ml] = acc[ct][r];
    }
  }
}

extern "C" void kernel_launch(void* const* d_in, const int* in_sizes, int n_in,
                              void* d_out, int out_size, void* d_ws, size_t ws_size,
                              hipStream_t stream) {
  const float* qx   = (const float*)d_in[0];
  const float* kvx  = (const float*)d_in[1];
  const float* bias = (const float*)d_in[2];
  const float* Wq   = (const float*)d_in[3];
  const float* Wk   = (const float*)d_in[4];
  const float* Wv   = (const float*)d_in[5];
  const float* Wg   = (const float*)d_in[6];
  const float* Wo   = (const float*)d_in[7];
  float* out = (float*)d_out;
  char* ws = (char*)d_ws;
  unsigned short* Xbq  = (unsigned short*)(ws);
  unsigned short* Xbkv = (unsigned short*)(ws + (1<<20));
  unsigned short* Wt4  = (unsigned short*)(ws + (2<<20));
  unsigned short* Wot  = (unsigned short*)(ws + (2<<20) + (512<<10));
  unsigned short* Qb   = (unsigned short*)(ws + (3<<20));
  unsigned short* Kb   = (unsigned short*)(ws + (4<<20));
  unsigned short* Vt   = (unsigned short*)(ws + (5<<20));
  unsigned short* Gg   = (unsigned short*)(ws + (6<<20));
  unsigned short* Og   = (unsigned short*)(ws + (7<<20));

  cvt_kernel<<<512, 256, 0, stream>>>(qx, kvx, Wq, Wk, Wv, Wg, Wo, Xbq, Xbkv, Wt4, Wot);
  dim3 gp(32, 16);
  proj_kernel<<<gp, 256, 0, stream>>>(Xbq, Xbkv, Wt4, Qb, Kb, Vt, Gg);
  attn_kernel<<<256, 256, 0, stream>>>(Qb, Kb, Vt, Gg, bias, Og);
  dim3 go(32, 4);
  oproj_kernel<<<go, 256, 0, stream>>>(Og, Wot, out);
}

// Round 2
// 70.723 us; speedup vs baseline: 1.7584x; 1.7584x over previous
//
#include <hip/hip_runtime.h>
#include <hip/hip_bf16.h>
#include <stdint.h>

typedef __attribute__((ext_vector_type(8))) short short8;
typedef __attribute__((ext_vector_type(8))) __bf16 bf16x8;
typedef __attribute__((ext_vector_type(4))) float f32x4;
typedef __attribute__((ext_vector_type(4))) unsigned short us4;
typedef unsigned int u32;
typedef __attribute__((address_space(3))) u32 lds_u32;
typedef const __attribute__((address_space(1))) u32 g_u32;

#define NSEQ 2048
#define L2E 1.44269504088896f

static __device__ __forceinline__ unsigned short f2bf(float x){
  union { float f; u32 u; } v; v.f = x;
  u32 r = v.u + 0x7fffu + ((v.u >> 16) & 1u);
  return (unsigned short)(r >> 16);
}
static __device__ __forceinline__ float bf2f(unsigned short s){
  union { float f; u32 u; } v; v.u = ((u32)s) << 16; return v.f;
}
static __device__ __forceinline__ void gload16(const void* g, void* l){
  __builtin_amdgcn_global_load_lds((g_u32*)g, (lds_u32*)l, 16, 0, 0);
}
static __device__ __forceinline__ f32x4 mfma16(bf16x8 a, bf16x8 b, f32x4 c){
  return __builtin_amdgcn_mfma_f32_16x16x32_bf16(a, b, c, 0, 0, 0);
}
static __device__ __forceinline__ bf16x8 ldfrag(const void* p){
  return *(const bf16x8*)p;
}

// ---------------- kernel 1: convert inputs to bf16, transpose weights ----------------
__global__ void cvt_kernel(const float* __restrict__ qx, const float* __restrict__ kvx,
                           const float* __restrict__ Wq, const float* __restrict__ Wk,
                           const float* __restrict__ Wv, const float* __restrict__ Wg,
                           const float* __restrict__ Wo,
                           unsigned short* __restrict__ Xbq, unsigned short* __restrict__ Xbkv,
                           unsigned short* __restrict__ Wt4, unsigned short* __restrict__ Wot){
  int stride = gridDim.x * blockDim.x;
  int tid = blockIdx.x * blockDim.x + threadIdx.x;
  for (int i = tid; i < NSEQ*256; i += stride){
    Xbq[i]  = f2bf(qx[i]);
    Xbkv[i] = f2bf(kvx[i]);
  }
  // weight transposes: Wt[o][i] = W[i][o]  (B^T form for the MFMA GEMMs)
  for (int j = tid; j < 5*65536; j += stride){
    int w = j >> 16, idx = j & 65535, o = idx >> 8, i = idx & 255;
    const float* W = (w==0)?Wq:((w==1)?Wk:((w==2)?Wv:((w==3)?Wg:Wo)));
    float v = W[i*256 + o];
    if (w == 0) v *= 0.17677669529663687f;  // fold 1/sqrt(32) into Wq
    if (w < 4) Wt4[w*65536 + o*256 + i] = f2bf(v);
    else       Wot[o*256 + i] = f2bf(v);
  }
}

// ---------------- kernel 2: fused QKVG projection GEMM ----------------
// C[2048, 1024] = X @ [Wq|Wk|Wv|Wg], tile 64x64, K=256 fully staged.
__global__ __launch_bounds__(256) void proj_kernel(const unsigned short* __restrict__ Xbq,
     const unsigned short* __restrict__ Xbkv, const unsigned short* __restrict__ Wt4,
     unsigned short* __restrict__ Qb, unsigned short* __restrict__ Kb,
     unsigned short* __restrict__ Vt, unsigned short* __restrict__ Gg){
  __shared__ unsigned short Asm[64*256];
  __shared__ unsigned short Bsm[64*256];
  int mt = blockIdx.x;            // 0..31
  int nt = blockIdx.y;            // 0..15
  int col0 = nt * 64;
  int w = col0 >> 8;              // which weight: 0=Q 1=K 2=V 3=G
  const unsigned short* A = (w==0 || w==3) ? Xbq : Xbkv;
  int tid = threadIdx.x, lane = tid & 63, wid = tid >> 6;
  const char* Ab = (const char*)A   + (size_t)mt*64*512;
  const char* Bb = (const char*)Wt4 + (size_t)col0*512;
  char* Asl = (char*)Asm; char* Bsl = (char*)Bsm;
  // stage both 32KB tiles; rows are 512B; XOR-swizzle f(row)=(row&15)<<4 applied
  // on the GLOBAL source so LDS dest stays linear (global_load_lds constraint).
  #pragma unroll
  for (int it = 0; it < 8; ++it){
    int o = it*4096 + wid*1024 + lane*16;
    int row = o >> 9, b = o & 511;
    int sb = (o & ~511) + (b ^ ((row & 15) << 4));
    gload16(Ab + sb, Asl + it*4096 + wid*1024);
    gload16(Bb + sb, Bsl + it*4096 + wid*1024);
  }
  __syncthreads();
  int ml = lane & 15, kg = lane >> 4;
  int m = wid*16 + ml;
  bf16x8 afr[8];
  #pragma unroll
  for (int ks = 0; ks < 8; ++ks)
    afr[ks] = ldfrag(Asl + m*512 + ((ks*64 + kg*16) ^ (ml << 4)));
  f32x4 acc[4];
  #pragma unroll
  for (int ct = 0; ct < 4; ++ct){
    acc[ct] = (f32x4){0.f,0.f,0.f,0.f};
    int oo = ct*16 + ml;
    #pragma unroll
    for (int ks = 0; ks < 8; ++ks){
      bf16x8 bfr = ldfrag(Bsl + oo*512 + ((ks*64 + kg*16) ^ (ml << 4)));
      acc[ct] = mfma16(afr[ks], bfr, acc[ct]);
    }
  }
  // epilogue: scatter to per-use layouts
  #pragma unroll
  for (int ct = 0; ct < 4; ++ct){
    int colg = col0 + ct*16 + ml;
    int cw = colg & 255, hh = cw >> 5, c = cw & 31;
    int n0 = mt*64 + wid*16 + kg*4;
    if (w == 2){
      // V stored transposed [h][c][n]; 4 consecutive n pack into one 8B store
      us4 pk;
      pk[0]=f2bf(acc[ct][0]); pk[1]=f2bf(acc[ct][1]);
      pk[2]=f2bf(acc[ct][2]); pk[3]=f2bf(acc[ct][3]);
      *(us4*)((char*)Vt + ((size_t)(hh*32 + c)*NSEQ + n0)*2) = pk;
    } else {
      #pragma unroll
      for (int r = 0; r < 4; ++r){
        int n = n0 + r;
        float v = acc[ct][r];
        if (w == 0)      Qb[((size_t)hh*NSEQ + n)*32 + c] = f2bf(v);
        else if (w == 1) Kb[((size_t)hh*NSEQ + n)*32 + c] = f2bf(v);
        else             Gg[(size_t)n*256 + cw] = f2bf(1.f/(1.f + __expf(-v)));
      }
    }
  }
}

// ---------------- kernel 3: fused bias-attention (flash-style) ----------------
// grid 256: one block per (head, 64-row q tile). 4 waves, each owns 16 q rows.
// Bias tile is staged to LDS via global_load_lds (dbuf) — NO register prefetch
// (round 1: runtime-indexed f32x4 breg[2][8] went to scratch -> 106 MB of HBM
// writes + full-latency critical path; rule #20).
__global__ __launch_bounds__(256) void attn_kernel(const unsigned short* __restrict__ Qb,
    const unsigned short* __restrict__ Kb, const unsigned short* __restrict__ Vt,
    const unsigned short* __restrict__ Gg, const float* __restrict__ bias,
    unsigned short* __restrict__ Og){
  __shared__ float Bs[2][8192];             // [64 q][128 kv] f32, dbuf, 64B-chunk swizzle
  __shared__ unsigned short Ksm[2][4096];   // [128 kv rows][32 c] bf16, dbuf
  __shared__ unsigned short Vsm[2][4096];   // [32 c][128 kv] bf16, dbuf
  __shared__ unsigned short Psm[8192];      // [64 q][128 kv] bf16
  int bid = blockIdx.x;
  int h = bid >> 5, qt = bid & 31;
  int q0 = qt * 64;
  int tid = threadIdx.x, lane = tid & 63, wid = tid >> 6;
  int ml = lane & 15, kg = lane >> 4;
  int qw = q0 + wid*16;
  bf16x8 qfr = ldfrag((const char*)Qb + (((size_t)h*NSEQ + qw + ml)*32 + kg*8)*2);
  const char* Kbase = (const char*)Kb + (size_t)h*NSEQ*32*2;
  const char* Vbase = (const char*)Vt + (size_t)h*32*NSEQ*2;
  const char* Bgbase = (const char*)(bias + (size_t)h*NSEQ*NSEQ) + (size_t)q0*8192;
  float mreg[4] = {-3e38f,-3e38f,-3e38f,-3e38f};
  float lreg[4] = {0.f,0.f,0.f,0.f};
  f32x4 oacc[2];
  oacc[0] = (f32x4){0.f,0.f,0.f,0.f};
  oacc[1] = (f32x4){0.f,0.f,0.f,0.f};

  auto stage = [&](int t, int buf){
    const char* Kt = Kbase + (size_t)t*128*64;   // tile contiguous: 128 rows * 64B
    char* Kl = (char*)&Ksm[buf][0];
    char* Vl = (char*)&Vsm[buf][0];
    #pragma unroll
    for (int it = 0; it < 2; ++it){
      int o = it*4096 + wid*1024 + lane*16;
      int n = o >> 6, b = o & 63;
      gload16(Kt + (o & ~63) + (b ^ ((((n>>1)&3)) << 4)), Kl + it*4096 + wid*1024);
      int c = o >> 8, vb = o & 255;
      gload16(Vbase + (size_t)c*4096 + (size_t)t*256 + (vb ^ ((c&15) << 4)),
              Vl + it*4096 + wid*1024);
    }
    // bias tile: 32 KB, dest linear, source pre-swizzled (swap 64B chunks on
    // kg-parity of the row) so C-layout ds_read_b32 is only 2-way-conflicted (free).
    const char* Bg = Bgbase + (size_t)t*512;
    char* Bl = (char*)&Bs[buf][0];
    #pragma unroll
    for (int it = 0; it < 8; ++it){
      int o = it*4096 + wid*1024 + lane*16;
      int row = o >> 9;
      int scb = (o & 511) ^ (((o >> 11) & 1) << 6);
      gload16(Bg + (size_t)row*8192 + scb, Bl + it*4096 + wid*1024);
    }
  };

  stage(0, 0);
  for (int t = 0; t < 16; ++t){
    int cur = t & 1;
    __syncthreads();   // staging(t) drained here (barrier implies vmcnt(0))
    // issue next tile's staging FIRST so HBM latency hides under this tile's compute
    if (t < 15) stage(t+1, cur^1);
    // S = bias + Q K^T   (acc initialized from LDS bias in C-fragment layout)
    const float* Bp = &Bs[cur][0];
    int colswz = (kg & 1) << 4;
    f32x4 s[8];
    #pragma unroll
    for (int ct = 0; ct < 8; ++ct){
      int colx = (ct*16 + ml) ^ colswz;
      f32x4 b;
      #pragma unroll
      for (int r = 0; r < 4; ++r)
        b[r] = Bp[(wid*16 + kg*4 + r)*128 + colx];
      int n = ct*16 + ml;
      bf16x8 kfr = ldfrag((char*)&Ksm[cur][0] + n*64 + ((kg*16) ^ (((n>>1)&3) << 4)));
      s[ct] = mfma16(qfr, kfr, b);
    }
    // online softmax over the wave's 16 rows (row r lives in 16 lanes of a quarter-group)
    float mx[4];
    #pragma unroll
    for (int r = 0; r < 4; ++r){
      mx[r] = s[0][r];
      #pragma unroll
      for (int ct = 1; ct < 8; ++ct) mx[r] = fmaxf(mx[r], s[ct][r]);
    }
    #pragma unroll
    for (int d = 1; d < 16; d <<= 1){
      #pragma unroll
      for (int r = 0; r < 4; ++r) mx[r] = fmaxf(mx[r], __shfl_xor(mx[r], d));
    }
    float sc[4], rs[4];
    #pragma unroll
    for (int r = 0; r < 4; ++r){
      float mn = fmaxf(mreg[r], mx[r]);
      sc[r] = exp2f((mreg[r] - mn) * L2E);
      mreg[r] = mn;
      rs[r] = 0.f;
    }
    #pragma unroll
    for (int ct = 0; ct < 8; ++ct){
      #pragma unroll
      for (int r = 0; r < 4; ++r){
        float pv = exp2f((s[ct][r] - mreg[r]) * L2E);
        s[ct][r] = pv;
        rs[r] += pv;
      }
    }
    #pragma unroll
    for (int d = 1; d < 16; d <<= 1){
      #pragma unroll
      for (int r = 0; r < 4; ++r) rs[r] += __shfl_xor(rs[r], d);
    }
    #pragma unroll
    for (int r = 0; r < 4; ++r) lreg[r] = lreg[r]*sc[r] + rs[r];
    #pragma unroll
    for (int c2 = 0; c2 < 2; ++c2){
      #pragma unroll
      for (int r = 0; r < 4; ++r) oacc[c2][r] *= sc[r];
    }
    // P -> LDS (bf16, XOR-swizzled rows); each wave touches only its own 16 rows
    #pragma unroll
    for (int ct = 0; ct < 8; ++ct){
      #pragma unroll
      for (int r = 0; r < 4; ++r){
        int q = wid*16 + kg*4 + r;
        int k = ct*16 + ml;
        *(unsigned short*)((char*)Psm + q*256 + ((k*2) ^ ((q&15) << 4))) = f2bf(s[ct][r]);
      }
    }
    // O += P V
    int qq = wid*16 + ml;
    #pragma unroll
    for (int ks = 0; ks < 4; ++ks){
      bf16x8 pfr = ldfrag((char*)Psm + qq*256 + ((ks*64 + kg*16) ^ ((qq&15) << 4)));
      #pragma unroll
      for (int c2 = 0; c2 < 2; ++c2){
        int c = c2*16 + ml;
        bf16x8 vfr = ldfrag((char*)&Vsm[cur][0] + c*256 + ((ks*64 + kg*16) ^ ((c&15) << 4)));
        oacc[c2] = mfma16(pfr, vfr, oacc[c2]);
      }
    }
  }
  // epilogue: O/l * gate -> Og bf16 [n][256]
  #pragma unroll
  for (int c2 = 0; c2 < 2; ++c2){
    #pragma unroll
    for (int r = 0; r < 4; ++r){
      int q = qw + kg*4 + r;
      int col = h*32 + c2*16 + ml;
      float g = bf2f(Gg[(size_t)q*256 + col]);
      float v = oacc[c2][r] / lreg[r] * g;
      Og[(size_t)q*256 + col] = f2bf(v);
    }
  }
}

// ---------------- kernel 4: output projection ----------------
__global__ __launch_bounds__(256) void oproj_kernel(const unsigned short* __restrict__ Og,
    const unsigned short* __restrict__ Wot, float* __restrict__ out){
  __shared__ unsigned short Asm[64*256];
  __shared__ unsigned short Bsm[64*256];
  int mt = blockIdx.x, nt = blockIdx.y;
  int col0 = nt * 64;
  int tid = threadIdx.x, lane = tid & 63, wid = tid >> 6;
  const char* Ab = (const char*)Og  + (size_t)mt*64*512;
  const char* Bb = (const char*)Wot + (size_t)col0*512;
  char* Asl = (char*)Asm; char* Bsl = (char*)Bsm;
  #pragma unroll
  for (int it = 0; it < 8; ++it){
    int o = it*4096 + wid*1024 + lane*16;
    int row = o >> 9, b = o & 511;
    int sb = (o & ~511) + (b ^ ((row & 15) << 4));
    gload16(Ab + sb, Asl + it*4096 + wid*1024);
    gload16(Bb + sb, Bsl + it*4096 + wid*1024);
  }
  __syncthreads();
  int ml = lane & 15, kg = lane >> 4;
  int m = wid*16 + ml;
  bf16x8 afr[8];
  #pragma unroll
  for (int ks = 0; ks < 8; ++ks)
    afr[ks] = ldfrag(Asl + m*512 + ((ks*64 + kg*16) ^ (ml << 4)));
  f32x4 acc[4];
  #pragma unroll
  for (int ct = 0; ct < 4; ++ct){
    acc[ct] = (f32x4){0.f,0.f,0.f,0.f};
    int oo = ct*16 + ml;
    #pragma unroll
    for (int ks = 0; ks < 8; ++ks){
      bf16x8 bfr = ldfrag(Bsl + oo*512 + ((ks*64 + kg*16) ^ (ml << 4)));
      acc[ct] = mfma16(afr[ks], bfr, acc[ct]);
    }
  }
  #pragma unroll
  for (int ct = 0; ct < 4; ++ct){
    #pragma unroll
    for (int r = 0; r < 4; ++r){
      int mm = mt*64 + wid*16 + kg*4 + r;
      out[(size_t)mm*256 + col0 + ct*16 + ml] = acc[ct][r];
    }
  }
}

extern "C" void kernel_launch(void* const* d_in, const int* in_sizes, int n_in,
                              void* d_out, int out_size, void* d_ws, size_t ws_size,
                              hipStream_t stream) {
  const float* qx   = (const float*)d_in[0];
  const float* kvx  = (const float*)d_in[1];
  const float* bias = (const float*)d_in[2];
  const float* Wq   = (const float*)d_in[3];
  const float* Wk   = (const float*)d_in[4];
  const float* Wv   = (const float*)d_in[5];
  const float* Wg   = (const float*)d_in[6];
  const float* Wo   = (const float*)d_in[7];
  float* out = (float*)d_out;
  char* ws = (char*)d_ws;
  unsigned short* Xbq  = (unsigned short*)(ws);
  unsigned short* Xbkv = (unsigned short*)(ws + (1<<20));
  unsigned short* Wt4  = (unsigned short*)(ws + (2<<20));
  unsigned short* Wot  = (unsigned short*)(ws + (2<<20) + (512<<10));
  unsigned short* Qb   = (unsigned short*)(ws + (3<<20));
  unsigned short* Kb   = (unsigned short*)(ws + (4<<20));
  unsigned short* Vt   = (unsigned short*)(ws + (5<<20));
  unsigned short* Gg   = (unsigned short*)(ws + (6<<20));
  unsigned short* Og   = (unsigned short*)(ws + (7<<20));

  cvt_kernel<<<512, 256, 0, stream>>>(qx, kvx, Wq, Wk, Wv, Wg, Wo, Xbq, Xbkv, Wt4, Wot);
  dim3 gp(32, 16);
  proj_kernel<<<gp, 256, 0, stream>>>(Xbq, Xbkv, Wt4, Qb, Kb, Vt, Gg);
  attn_kernel<<<256, 256, 0, stream>>>(Qb, Kb, Vt, Gg, bias, Og);
  dim3 go(32, 4);
  oproj_kernel<<<go, 256, 0, stream>>>(Og, Wot, out);
}

// Round 3
// 68.522 us; speedup vs baseline: 1.8149x; 1.0321x over previous
//
#include <hip/hip_runtime.h>
#include <hip/hip_bf16.h>
#include <stdint.h>

typedef __attribute__((ext_vector_type(8))) short short8;
typedef __attribute__((ext_vector_type(8))) __bf16 bf16x8;
typedef __attribute__((ext_vector_type(4))) float f32x4;
typedef __attribute__((ext_vector_type(4))) float float4v;
typedef __attribute__((ext_vector_type(4))) unsigned short us4;
typedef unsigned int u32;
typedef __attribute__((address_space(3))) u32 lds_u32;
typedef const __attribute__((address_space(1))) u32 g_u32;

#define NSEQ 2048
#define L2E 1.44269504088896f

static __device__ __forceinline__ unsigned short f2bf(float x){
  union { float f; u32 u; } v; v.f = x;
  u32 r = v.u + 0x7fffu + ((v.u >> 16) & 1u);
  return (unsigned short)(r >> 16);
}
static __device__ __forceinline__ float bf2f(unsigned short s){
  union { float f; u32 u; } v; v.u = ((u32)s) << 16; return v.f;
}
static __device__ __forceinline__ void gload16(const void* g, void* l){
  __builtin_amdgcn_global_load_lds((g_u32*)g, (lds_u32*)l, 16, 0, 0);
}
static __device__ __forceinline__ f32x4 mfma16(bf16x8 a, bf16x8 b, f32x4 c){
  return __builtin_amdgcn_mfma_f32_16x16x32_bf16(a, b, c, 0, 0, 0);
}
static __device__ __forceinline__ bf16x8 ldfrag(const void* p){
  return *(const bf16x8*)p;
}
#define MEMFENCE() asm volatile("" ::: "memory")

// ---------------- kernel 1: convert inputs to bf16, transpose weights ----------------
// blocks 0..511: vectorized X conversion. blocks 512..591: LDS-tiled weight transpose.
__global__ __launch_bounds__(256) void cvt_kernel(const float* __restrict__ qx,
                           const float* __restrict__ kvx,
                           const float* __restrict__ Wq, const float* __restrict__ Wk,
                           const float* __restrict__ Wv, const float* __restrict__ Wg,
                           const float* __restrict__ Wo,
                           unsigned short* __restrict__ Xbq, unsigned short* __restrict__ Xbkv,
                           unsigned short* __restrict__ Wt4, unsigned short* __restrict__ Wot){
  __shared__ float T[64][65];
  int bid = blockIdx.x;
  if (bid < 512){
    int i4 = (bid*256 + threadIdx.x) * 4;   // covers 2048*256 exactly
    float4v q = *(const float4v*)(qx + i4);
    float4v k = *(const float4v*)(kvx + i4);
    us4 qo, ko;
    #pragma unroll
    for (int j = 0; j < 4; ++j){ qo[j] = f2bf(q[j]); ko[j] = f2bf(k[j]); }
    *(us4*)(Xbq + i4) = qo;
    *(us4*)(Xbkv + i4) = ko;
  } else {
    int b2 = bid - 512;                     // 0..79
    int w = b2 >> 4, tile = b2 & 15, tr = tile >> 2, tc = tile & 3;
    const float* W = (w==0)?Wq:((w==1)?Wk:((w==2)?Wv:((w==3)?Wg:Wo)));
    int t = threadIdx.x;
    int rl = t >> 4, cq = t & 15;
    #pragma unroll
    for (int p = 0; p < 4; ++p){
      int r = p*16 + rl;
      float4v v = *(const float4v*)(W + (size_t)(tr*64 + r)*256 + tc*64 + cq*4);
      #pragma unroll
      for (int j = 0; j < 4; ++j) T[r][cq*4+j] = v[j];
    }
    __syncthreads();
    float s = (w==0) ? 0.17677669529663687f : 1.f;   // fold 1/sqrt(32) into Wq
    #pragma unroll
    for (int p = 0; p < 4; ++p){
      int o = p*16 + rl;
      us4 pk;
      #pragma unroll
      for (int j = 0; j < 4; ++j) pk[j] = f2bf(T[cq*4+j][o] * s);
      int og = tc*64 + o, ig = tr*64 + cq*4;
      if (w < 4) *(us4*)(Wt4 + (size_t)w*65536 + og*256 + ig) = pk;
      else       *(us4*)(Wot + (size_t)og*256 + ig) = pk;
    }
  }
}

// ---------------- kernel 2: fused QKVG projection GEMM ----------------
// C[2048, 1024] = X @ [Wq|Wk|Wv|Wg], tile 64x64, K=256 fully staged.
__global__ __launch_bounds__(256) void proj_kernel(const unsigned short* __restrict__ Xbq,
     const unsigned short* __restrict__ Xbkv, const unsigned short* __restrict__ Wt4,
     unsigned short* __restrict__ Qb, unsigned short* __restrict__ Kb,
     unsigned short* __restrict__ Vt, unsigned short* __restrict__ Gg){
  __shared__ unsigned short Asm[64*256];
  __shared__ unsigned short Bsm[64*256];
  int mt = blockIdx.x;            // 0..31
  int nt = blockIdx.y;            // 0..15
  int col0 = nt * 64;
  int w = col0 >> 8;              // which weight: 0=Q 1=K 2=V 3=G
  const unsigned short* A = (w==0 || w==3) ? Xbq : Xbkv;
  int tid = threadIdx.x, lane = tid & 63, wid = tid >> 6;
  const char* Ab = (const char*)A   + (size_t)mt*64*512;
  const char* Bb = (const char*)Wt4 + (size_t)col0*512;
  char* Asl = (char*)Asm; char* Bsl = (char*)Bsm;
  // stage both 32KB tiles; rows are 512B; XOR-swizzle f(row)=(row&15)<<4 applied
  // on the GLOBAL source so LDS dest stays linear (global_load_lds constraint).
  #pragma unroll
  for (int it = 0; it < 8; ++it){
    int o = it*4096 + wid*1024 + lane*16;
    int row = o >> 9, b = o & 511;
    int sb = (o & ~511) + (b ^ ((row & 15) << 4));
    gload16(Ab + sb, Asl + it*4096 + wid*1024);
    gload16(Bb + sb, Bsl + it*4096 + wid*1024);
  }
  __syncthreads();
  int ml = lane & 15, kg = lane >> 4;
  int m = wid*16 + ml;
  bf16x8 afr[8];
  #pragma unroll
  for (int ks = 0; ks < 8; ++ks)
    afr[ks] = ldfrag(Asl + m*512 + ((ks*64 + kg*16) ^ (ml << 4)));
  f32x4 acc[4];
  #pragma unroll
  for (int ct = 0; ct < 4; ++ct){
    acc[ct] = (f32x4){0.f,0.f,0.f,0.f};
    int oo = ct*16 + ml;
    #pragma unroll
    for (int ks = 0; ks < 8; ++ks){
      bf16x8 bfr = ldfrag(Bsl + oo*512 + ((ks*64 + kg*16) ^ (ml << 4)));
      acc[ct] = mfma16(afr[ks], bfr, acc[ct]);
    }
  }
  // epilogue: scatter to per-use layouts
  #pragma unroll
  for (int ct = 0; ct < 4; ++ct){
    int colg = col0 + ct*16 + ml;
    int cw = colg & 255, hh = cw >> 5, c = cw & 31;
    int n0 = mt*64 + wid*16 + kg*4;
    if (w == 2){
      // V stored transposed [h][c][n]; 4 consecutive n pack into one 8B store
      us4 pk;
      pk[0]=f2bf(acc[ct][0]); pk[1]=f2bf(acc[ct][1]);
      pk[2]=f2bf(acc[ct][2]); pk[3]=f2bf(acc[ct][3]);
      *(us4*)((char*)Vt + ((size_t)(hh*32 + c)*NSEQ + n0)*2) = pk;
    } else {
      #pragma unroll
      for (int r = 0; r < 4; ++r){
        int n = n0 + r;
        float v = acc[ct][r];
        if (w == 0)      Qb[((size_t)hh*NSEQ + n)*32 + c] = f2bf(v);
        else if (w == 1) Kb[((size_t)hh*NSEQ + n)*32 + c] = f2bf(v);
        else             Gg[(size_t)n*256 + cw] = f2bf(1.f/(1.f + __expf(-v)));
      }
    }
  }
}

// ---------------- kernel 3: fused bias-attention (flash-style) ----------------
// grid 256: one block per (head, 64-row q tile). 4 waves, each owns 16 q rows.
// 3-buffer pipeline, prefetch distance 2, raw s_barrier + counted vmcnt(12):
// the stage landing-wait is for loads issued TWO iterations ago (already done)
// so the issue stream never drains (T3+T4). Two barriers/iter:
//   #1 (after vmcnt): tile-t data fresh for all waves; #2: all waves done
//   reading before buf (t+2)%3 (== (t-1)%3) is re-staged (WAR).
__global__ __launch_bounds__(256) void attn_kernel(const unsigned short* __restrict__ Qb,
    const unsigned short* __restrict__ Kb, const unsigned short* __restrict__ Vt,
    const unsigned short* __restrict__ Gg, const float* __restrict__ bias,
    unsigned short* __restrict__ Og){
  __shared__ float Bs[3][8192];             // [64 q][128 kv] f32, 64B-chunk swizzle
  __shared__ unsigned short Ksm[3][4096];   // [128 kv rows][32 c] bf16
  __shared__ unsigned short Vsm[3][4096];   // [32 c][128 kv] bf16
  __shared__ unsigned short Psm[8192];      // [64 q][128 kv] bf16 (wave-local rows)
  int bid = blockIdx.x;
  int h = bid >> 5, qt = bid & 31;
  int q0 = qt * 64;
  int tid = threadIdx.x, lane = tid & 63, wid = tid >> 6;
  int ml = lane & 15, kg = lane >> 4;
  int qw = q0 + wid*16;
  bf16x8 qfr = ldfrag((const char*)Qb + (((size_t)h*NSEQ + qw + ml)*32 + kg*8)*2);
  const char* Kbase = (const char*)Kb + (size_t)h*NSEQ*32*2;
  const char* Vbase = (const char*)Vt + (size_t)h*32*NSEQ*2;
  const char* Bgbase = (const char*)(bias + (size_t)h*NSEQ*NSEQ) + (size_t)q0*8192;
  float mreg[4] = {-3e38f,-3e38f,-3e38f,-3e38f};
  float lreg[4] = {0.f,0.f,0.f,0.f};
  f32x4 oacc[2];
  oacc[0] = (f32x4){0.f,0.f,0.f,0.f};
  oacc[1] = (f32x4){0.f,0.f,0.f,0.f};

  auto stage = [&](int t, int buf){
    const char* Kt = Kbase + (size_t)t*128*64;   // tile contiguous: 128 rows * 64B
    char* Kl = (char*)&Ksm[buf][0];
    char* Vl = (char*)&Vsm[buf][0];
    #pragma unroll
    for (int it = 0; it < 2; ++it){
      int o = it*4096 + wid*1024 + lane*16;
      int n = o >> 6, b = o & 63;
      gload16(Kt + (o & ~63) + (b ^ ((((n>>1)&3)) << 4)), Kl + it*4096 + wid*1024);
      int c = o >> 8, vb = o & 255;
      gload16(Vbase + (size_t)c*4096 + (size_t)t*256 + (vb ^ ((c&15) << 4)),
              Vl + it*4096 + wid*1024);
    }
    // bias tile: 32 KB, dest linear, source pre-swizzled (swap 64B chunks on
    // kg-parity of the row) so C-layout ds_read_b32 is only 2-way-conflicted (free).
    const char* Bg = Bgbase + (size_t)t*512;
    char* Bl = (char*)&Bs[buf][0];
    #pragma unroll
    for (int it = 0; it < 8; ++it){
      int o = it*4096 + wid*1024 + lane*16;
      int row = o >> 9;
      int scb = (o & 511) ^ (((o >> 11) & 1) << 6);
      gload16(Bg + (size_t)row*8192 + scb, Bl + it*4096 + wid*1024);
    }
  };

  stage(0, 0);
  stage(1, 1);
  for (int t = 0; t < 16; ++t){
    int cur = t % 3;
    // wait: my loads from 2 iters ago landed (12 = one stage's loads outstanding max
    // beyond that); other waves' same guarantee is transported by barrier #1.
    if (t == 15) asm volatile("s_waitcnt vmcnt(0)" ::: "memory");
    else         asm volatile("s_waitcnt vmcnt(12)" ::: "memory");
    __builtin_amdgcn_s_barrier();
    MEMFENCE();
    // S = bias + Q K^T   (acc initialized from LDS bias in C-fragment layout)
    const float* Bp = &Bs[cur][0];
    int colswz = (kg & 1) << 4;
    f32x4 s[8];
    #pragma unroll
    for (int ct = 0; ct < 8; ++ct){
      int colx = (ct*16 + ml) ^ colswz;
      f32x4 b;
      #pragma unroll
      for (int r = 0; r < 4; ++r)
        b[r] = Bp[(wid*16 + kg*4 + r)*128 + colx];
      int n = ct*16 + ml;
      bf16x8 kfr = ldfrag((char*)&Ksm[cur][0] + n*64 + ((kg*16) ^ (((n>>1)&3) << 4)));
      s[ct] = mfma16(qfr, kfr, b);
    }
    // online softmax over the wave's 16 rows (row r lives in 16 lanes of a quarter-group)
    float mx[4];
    #pragma unroll
    for (int r = 0; r < 4; ++r){
      mx[r] = s[0][r];
      #pragma unroll
      for (int ct = 1; ct < 8; ++ct) mx[r] = fmaxf(mx[r], s[ct][r]);
    }
    #pragma unroll
    for (int d = 1; d < 16; d <<= 1){
      #pragma unroll
      for (int r = 0; r < 4; ++r) mx[r] = fmaxf(mx[r], __shfl_xor(mx[r], d));
    }
    float sc[4], rs[4];
    #pragma unroll
    for (int r = 0; r < 4; ++r){
      float mn = fmaxf(mreg[r], mx[r]);
      sc[r] = exp2f((mreg[r] - mn) * L2E);
      mreg[r] = mn;
      rs[r] = 0.f;
    }
    #pragma unroll
    for (int ct = 0; ct < 8; ++ct){
      #pragma unroll
      for (int r = 0; r < 4; ++r){
        float pv = exp2f((s[ct][r] - mreg[r]) * L2E);
        s[ct][r] = pv;
        rs[r] += pv;
      }
    }
    #pragma unroll
    for (int d = 1; d < 16; d <<= 1){
      #pragma unroll
      for (int r = 0; r < 4; ++r) rs[r] += __shfl_xor(rs[r], d);
    }
    #pragma unroll
    for (int r = 0; r < 4; ++r) lreg[r] = lreg[r]*sc[r] + rs[r];
    #pragma unroll
    for (int c2 = 0; c2 < 2; ++c2){
      #pragma unroll
      for (int r = 0; r < 4; ++r) oacc[c2][r] *= sc[r];
    }
    // P -> LDS (bf16, XOR-swizzled rows); each wave touches only its own 16 rows
    #pragma unroll
    for (int ct = 0; ct < 8; ++ct){
      #pragma unroll
      for (int r = 0; r < 4; ++r){
        int q = wid*16 + kg*4 + r;
        int k = ct*16 + ml;
        *(unsigned short*)((char*)Psm + q*256 + ((k*2) ^ ((q&15) << 4))) = f2bf(s[ct][r]);
      }
    }
    // O += P V
    int qq = wid*16 + ml;
    #pragma unroll
    for (int ks = 0; ks < 4; ++ks){
      bf16x8 pfr = ldfrag((char*)Psm + qq*256 + ((ks*64 + kg*16) ^ ((qq&15) << 4)));
      #pragma unroll
      for (int c2 = 0; c2 < 2; ++c2){
        int c = c2*16 + ml;
        bf16x8 vfr = ldfrag((char*)&Vsm[cur][0] + c*256 + ((ks*64 + kg*16) ^ ((c&15) << 4)));
        oacc[c2] = mfma16(pfr, vfr, oacc[c2]);
      }
    }
    MEMFENCE();
    __builtin_amdgcn_s_barrier();   // WAR: everyone done reading tile t
    MEMFENCE();
    if (t < 14) stage(t+2, (t+2) % 3);
  }
  // epilogue: O/l * gate -> Og bf16 [n][256]
  #pragma unroll
  for (int c2 = 0; c2 < 2; ++c2){
    #pragma unroll
    for (int r = 0; r < 4; ++r){
      int q = qw + kg*4 + r;
      int col = h*32 + c2*16 + ml;
      float g = bf2f(Gg[(size_t)q*256 + col]);
      float v = oacc[c2][r] / lreg[r] * g;
      Og[(size_t)q*256 + col] = f2bf(v);
    }
  }
}

// ---------------- kernel 4: output projection ----------------
__global__ __launch_bounds__(256) void oproj_kernel(const unsigned short* __restrict__ Og,
    const unsigned short* __restrict__ Wot, float* __restrict__ out){
  __shared__ unsigned short Asm[64*256];
  __shared__ unsigned short Bsm[64*256];
  int mt = blockIdx.x, nt = blockIdx.y;
  int col0 = nt * 64;
  int tid = threadIdx.x, lane = tid & 63, wid = tid >> 6;
  const char* Ab = (const char*)Og  + (size_t)mt*64*512;
  const char* Bb = (const char*)Wot + (size_t)col0*512;
  char* Asl = (char*)Asm; char* Bsl = (char*)Bsm;
  #pragma unroll
  for (int it = 0; it < 8; ++it){
    int o = it*4096 + wid*1024 + lane*16;
    int row = o >> 9, b = o & 511;
    int sb = (o & ~511) + (b ^ ((row & 15) << 4));
    gload16(Ab + sb, Asl + it*4096 + wid*1024);
    gload16(Bb + sb, Bsl + it*4096 + wid*1024);
  }
  __syncthreads();
  int ml = lane & 15, kg = lane >> 4;
  int m = wid*16 + ml;
  bf16x8 afr[8];
  #pragma unroll
  for (int ks = 0; ks < 8; ++ks)
    afr[ks] = ldfrag(Asl + m*512 + ((ks*64 + kg*16) ^ (ml << 4)));
  f32x4 acc[4];
  #pragma unroll
  for (int ct = 0; ct < 4; ++ct){
    acc[ct] = (f32x4){0.f,0.f,0.f,0.f};
    int oo = ct*16 + ml;
    #pragma unroll
    for (int ks = 0; ks < 8; ++ks){
      bf16x8 bfr = ldfrag(Bsl + oo*512 + ((ks*64 + kg*16) ^ (ml << 4)));
      acc[ct] = mfma16(afr[ks], bfr, acc[ct]);
    }
  }
  #pragma unroll
  for (int ct = 0; ct < 4; ++ct){
    #pragma unroll
    for (int r = 0; r < 4; ++r){
      int mm = mt*64 + wid*16 + kg*4 + r;
      out[(size_t)mm*256 + col0 + ct*16 + ml] = acc[ct][r];
    }
  }
}

extern "C" void kernel_launch(void* const* d_in, const int* in_sizes, int n_in,
                              void* d_out, int out_size, void* d_ws, size_t ws_size,
                              hipStream_t stream) {
  const float* qx   = (const float*)d_in[0];
  const float* kvx  = (const float*)d_in[1];
  const float* bias = (const float*)d_in[2];
  const float* Wq   = (const float*)d_in[3];
  const float* Wk   = (const float*)d_in[4];
  const float* Wv   = (const float*)d_in[5];
  const float* Wg   = (const float*)d_in[6];
  const float* Wo   = (const float*)d_in[7];
  float* out = (float*)d_out;
  char* ws = (char*)d_ws;
  unsigned short* Xbq  = (unsigned short*)(ws);
  unsigned short* Xbkv = (unsigned short*)(ws + (1<<20));
  unsigned short* Wt4  = (unsigned short*)(ws + (2<<20));
  unsigned short* Wot  = (unsigned short*)(ws + (2<<20) + (512<<10));
  unsigned short* Qb   = (unsigned short*)(ws + (3<<20));
  unsigned short* Kb   = (unsigned short*)(ws + (4<<20));
  unsigned short* Vt   = (unsigned short*)(ws + (5<<20));
  unsigned short* Gg   = (unsigned short*)(ws + (6<<20));
  unsigned short* Og   = (unsigned short*)(ws + (7<<20));

  cvt_kernel<<<592, 256, 0, stream>>>(qx, kvx, Wq, Wk, Wv, Wg, Wo, Xbq, Xbkv, Wt4, Wot);
  dim3 gp(32, 16);
  proj_kernel<<<gp, 256, 0, stream>>>(Xbq, Xbkv, Wt4, Qb, Kb, Vt, Gg);
  attn_kernel<<<256, 256, 0, stream>>>(Qb, Kb, Vt, Gg, bias, Og);
  dim3 go(32, 4);
  oproj_kernel<<<go, 256, 0, stream>>>(Og, Wot, out);
}

// Round 4
// 56.679 us; speedup vs baseline: 2.1941x; 1.2089x over previous
//
#include <hip/hip_runtime.h>
#include <hip/hip_bf16.h>
#include <stdint.h>

typedef __attribute__((ext_vector_type(8))) short short8;
typedef __attribute__((ext_vector_type(8))) __bf16 bf16x8;
typedef __attribute__((ext_vector_type(4))) float f32x4;
typedef __attribute__((ext_vector_type(4))) float float4v;
typedef __attribute__((ext_vector_type(4))) unsigned short us4;
typedef unsigned int u32;
typedef __attribute__((address_space(3))) u32 lds_u32;
typedef const __attribute__((address_space(1))) u32 g_u32;

#define NSEQ 2048
#define L2E 1.44269504088896f

static __device__ __forceinline__ unsigned short f2bf(float x){
  union { float f; u32 u; } v; v.f = x;
  u32 r = v.u + 0x7fffu + ((v.u >> 16) & 1u);
  return (unsigned short)(r >> 16);
}
static __device__ __forceinline__ float bf2f(unsigned short s){
  union { float f; u32 u; } v; v.u = ((u32)s) << 16; return v.f;
}
static __device__ __forceinline__ void gload16(const void* g, void* l){
  __builtin_amdgcn_global_load_lds((g_u32*)g, (lds_u32*)l, 16, 0, 0);
}
static __device__ __forceinline__ f32x4 mfma16(bf16x8 a, bf16x8 b, f32x4 c){
  return __builtin_amdgcn_mfma_f32_16x16x32_bf16(a, b, c, 0, 0, 0);
}
static __device__ __forceinline__ bf16x8 ldfrag(const void* p){
  return *(const bf16x8*)p;
}
#define MEMFENCE() asm volatile("" ::: "memory")

// ---------------- kernel 1: convert inputs to bf16, transpose weights ----------------
__global__ __launch_bounds__(256) void cvt_kernel(const float* __restrict__ qx,
                           const float* __restrict__ kvx,
                           const float* __restrict__ Wq, const float* __restrict__ Wk,
                           const float* __restrict__ Wv, const float* __restrict__ Wg,
                           const float* __restrict__ Wo,
                           unsigned short* __restrict__ Xbq, unsigned short* __restrict__ Xbkv,
                           unsigned short* __restrict__ Wt4, unsigned short* __restrict__ Wot){
  __shared__ float T[64][65];
  int bid = blockIdx.x;
  if (bid < 512){
    int i4 = (bid*256 + threadIdx.x) * 4;
    float4v q = *(const float4v*)(qx + i4);
    float4v k = *(const float4v*)(kvx + i4);
    us4 qo, ko;
    #pragma unroll
    for (int j = 0; j < 4; ++j){ qo[j] = f2bf(q[j]); ko[j] = f2bf(k[j]); }
    *(us4*)(Xbq + i4) = qo;
    *(us4*)(Xbkv + i4) = ko;
  } else {
    int b2 = bid - 512;                     // 0..79
    int w = b2 >> 4, tile = b2 & 15, tr = tile >> 2, tc = tile & 3;
    const float* W = (w==0)?Wq:((w==1)?Wk:((w==2)?Wv:((w==3)?Wg:Wo)));
    int t = threadIdx.x;
    int rl = t >> 4, cq = t & 15;
    #pragma unroll
    for (int p = 0; p < 4; ++p){
      int r = p*16 + rl;
      float4v v = *(const float4v*)(W + (size_t)(tr*64 + r)*256 + tc*64 + cq*4);
      #pragma unroll
      for (int j = 0; j < 4; ++j) T[r][cq*4+j] = v[j];
    }
    __syncthreads();
    float s = (w==0) ? 0.17677669529663687f : 1.f;   // fold 1/sqrt(32) into Wq
    #pragma unroll
    for (int p = 0; p < 4; ++p){
      int o = p*16 + rl;
      us4 pk;
      #pragma unroll
      for (int j = 0; j < 4; ++j) pk[j] = f2bf(T[cq*4+j][o] * s);
      int og = tc*64 + o, ig = tr*64 + cq*4;
      if (w < 4) *(us4*)(Wt4 + (size_t)w*65536 + og*256 + ig) = pk;
      else       *(us4*)(Wot + (size_t)og*256 + ig) = pk;
    }
  }
}

// ---------------- kernel 2: fused QKVG projection GEMM ----------------
__global__ __launch_bounds__(256) void proj_kernel(const unsigned short* __restrict__ Xbq,
     const unsigned short* __restrict__ Xbkv, const unsigned short* __restrict__ Wt4,
     unsigned short* __restrict__ Qb, unsigned short* __restrict__ Kb,
     unsigned short* __restrict__ Vt, unsigned short* __restrict__ Gg){
  __shared__ unsigned short Asm[64*256];
  __shared__ unsigned short Bsm[64*256];
  int mt = blockIdx.x;            // 0..31
  int nt = blockIdx.y;            // 0..15
  int col0 = nt * 64;
  int w = col0 >> 8;              // 0=Q 1=K 2=V 3=G
  const unsigned short* A = (w==0 || w==3) ? Xbq : Xbkv;
  int tid = threadIdx.x, lane = tid & 63, wid = tid >> 6;
  const char* Ab = (const char*)A   + (size_t)mt*64*512;
  const char* Bb = (const char*)Wt4 + (size_t)col0*512;
  char* Asl = (char*)Asm; char* Bsl = (char*)Bsm;
  #pragma unroll
  for (int it = 0; it < 8; ++it){
    int o = it*4096 + wid*1024 + lane*16;
    int row = o >> 9, b = o & 511;
    int sb = (o & ~511) + (b ^ ((row & 15) << 4));
    gload16(Ab + sb, Asl + it*4096 + wid*1024);
    gload16(Bb + sb, Bsl + it*4096 + wid*1024);
  }
  __syncthreads();
  int ml = lane & 15, kg = lane >> 4;
  int m = wid*16 + ml;
  bf16x8 afr[8];
  #pragma unroll
  for (int ks = 0; ks < 8; ++ks)
    afr[ks] = ldfrag(Asl + m*512 + ((ks*64 + kg*16) ^ (ml << 4)));
  f32x4 acc[4];
  #pragma unroll
  for (int ct = 0; ct < 4; ++ct){
    acc[ct] = (f32x4){0.f,0.f,0.f,0.f};
    int oo = ct*16 + ml;
    #pragma unroll
    for (int ks = 0; ks < 8; ++ks){
      bf16x8 bfr = ldfrag(Bsl + oo*512 + ((ks*64 + kg*16) ^ (ml << 4)));
      acc[ct] = mfma16(afr[ks], bfr, acc[ct]);
    }
  }
  #pragma unroll
  for (int ct = 0; ct < 4; ++ct){
    int colg = col0 + ct*16 + ml;
    int cw = colg & 255, hh = cw >> 5, c = cw & 31;
    int n0 = mt*64 + wid*16 + kg*4;
    if (w == 2){
      us4 pk;
      pk[0]=f2bf(acc[ct][0]); pk[1]=f2bf(acc[ct][1]);
      pk[2]=f2bf(acc[ct][2]); pk[3]=f2bf(acc[ct][3]);
      *(us4*)((char*)Vt + ((size_t)(hh*32 + c)*NSEQ + n0)*2) = pk;
    } else {
      #pragma unroll
      for (int r = 0; r < 4; ++r){
        int n = n0 + r;
        float v = acc[ct][r];
        if (w == 0)      Qb[((size_t)hh*NSEQ + n)*32 + c] = f2bf(v);
        else if (w == 1) Kb[((size_t)hh*NSEQ + n)*32 + c] = f2bf(v);
        else             Gg[(size_t)n*256 + cw] = f2bf(1.f/(1.f + __expf(-v)));
      }
    }
  }
}

// ---------------- kernel 3: fused bias-attention, kv-split ----------------
// grid 1024 = 8 heads x 32 q-tiles(64) x 4 kv-chunks(512). 4 waves/block.
// LDS 40KB -> 4 blocks/CU -> 16 waves/CU: latency (shuffle chains, exp2, bias
// loads) hidden by wave-level parallelism instead of a deep pipeline.
// Bias loads go DIRECT to VGPRs (static-indexed bb[4][4], full unroll).
// K/V: 4 LDS buffers, distance-2 prefetch, ONE barrier/tile, vmcnt(2) counted.
__global__ __launch_bounds__(256, 4) void attn_kernel(const unsigned short* __restrict__ Qb,
    const unsigned short* __restrict__ Kb, const unsigned short* __restrict__ Vt,
    const float* __restrict__ bias,
    float* __restrict__ Opart, float* __restrict__ Mpart, float* __restrict__ Lpart){
  __shared__ unsigned short Ksm[4][2048];   // [64 kv][32 c] bf16, 4 bufs
  __shared__ unsigned short Vsm[4][2048];   // [32 c][64 kv] bf16, 4 bufs
  __shared__ unsigned short Psm[4096];      // [64 q][64 kv] bf16 (wave-local rows)
  int bid = blockIdx.x;
  int h = bid >> 7, qt = (bid >> 2) & 31, ch = bid & 3;
  int q0 = qt * 64;
  int tid = threadIdx.x, lane = tid & 63, wid = tid >> 6;
  int ml = lane & 15, kg = lane >> 4;
  int qw = q0 + wid*16;
  bf16x8 qfr = ldfrag((const char*)Qb + (((size_t)h*NSEQ + qw + ml)*32 + kg*8)*2);
  const char* Kbase = (const char*)Kb + (size_t)h*NSEQ*32*2;
  const char* Vbase = (const char*)Vt + (size_t)h*32*NSEQ*2;
  // lane-private bias base: row (qw+kg*4), col chunk start + ml
  const float* bias_l = bias + (size_t)h*NSEQ*NSEQ + (size_t)(qw + kg*4)*NSEQ + ch*512 + ml;
  float mreg[4] = {-3e38f,-3e38f,-3e38f,-3e38f};
  float lreg[4] = {0.f,0.f,0.f,0.f};
  f32x4 oacc[2];
  oacc[0] = (f32x4){0.f,0.f,0.f,0.f};
  oacc[1] = (f32x4){0.f,0.f,0.f,0.f};

  auto stage = [&](int t, int buf){   // t = tile within chunk (0..7)
    int tg = ch*8 + t;                // global 64-kv tile
    int o = tid*16;
    // K: [64 n][32 c] rows 64B; swizzle keeps kfr reads bank-uniform
    int n = o >> 6, kb = o & 63;
    gload16(Kbase + (size_t)tg*4096 + (o & ~63) + (kb ^ (((n>>1)&3) << 4)),
            (char*)&Ksm[buf][0] + o);
    // V: [32 c][64 n] rows 128B; swizzle by (c&7)
    int c = o >> 7, vb = o & 127;
    gload16(Vbase + (size_t)c*4096 + (size_t)tg*128 + (vb ^ ((c&7) << 4)),
            (char*)&Vsm[buf][0] + o);
  };

  stage(0, 0);
  stage(1, 1);
  for (int t = 0; t < 8; ++t){
    int cur = t & 3;
    // own KV(t) landed (only KV(t+1) may stay in flight); barrier transports
    // the same guarantee from the other 3 waves.
    if (t == 7) asm volatile("s_waitcnt vmcnt(0)" ::: "memory");
    else        asm volatile("s_waitcnt vmcnt(2)" ::: "memory");
    __builtin_amdgcn_s_barrier();
    MEMFENCE();
    if (t < 6) stage(t+2, (t+2) & 3);   // WAR-safe: 2 barriers since last read
    // bias for THIS tile, direct to regs (latency hidden by 16 waves/CU)
    float bb[4][4];
    #pragma unroll
    for (int ct = 0; ct < 4; ++ct){
      #pragma unroll
      for (int r = 0; r < 4; ++r)
        bb[ct][r] = bias_l[(size_t)r*NSEQ + t*64 + ct*16];
    }
    // S = bias + Q K^T
    f32x4 s[4];
    #pragma unroll
    for (int ct = 0; ct < 4; ++ct){
      f32x4 b;
      #pragma unroll
      for (int r = 0; r < 4; ++r) b[r] = bb[ct][r];
      int n = ct*16 + ml;
      bf16x8 kfr = ldfrag((char*)&Ksm[cur][0] + n*64 + ((kg*16) ^ (((n>>1)&3) << 4)));
      s[ct] = mfma16(qfr, kfr, b);
    }
    // online softmax (16 rows/wave; row r lives across 16 ml lanes)
    float mx[4];
    #pragma unroll
    for (int r = 0; r < 4; ++r){
      mx[r] = fmaxf(fmaxf(s[0][r], s[1][r]), fmaxf(s[2][r], s[3][r]));
    }
    #pragma unroll
    for (int d = 1; d < 16; d <<= 1){
      #pragma unroll
      for (int r = 0; r < 4; ++r) mx[r] = fmaxf(mx[r], __shfl_xor(mx[r], d));
    }
    float sc[4], rs[4];
    #pragma unroll
    for (int r = 0; r < 4; ++r){
      float mn = fmaxf(mreg[r], mx[r]);
      sc[r] = exp2f((mreg[r] - mn) * L2E);
      mreg[r] = mn;
      rs[r] = 0.f;
    }
    #pragma unroll
    for (int ct = 0; ct < 4; ++ct){
      #pragma unroll
      for (int r = 0; r < 4; ++r){
        float pv = exp2f((s[ct][r] - mreg[r]) * L2E);
        s[ct][r] = pv;
        rs[r] += pv;
      }
    }
    #pragma unroll
    for (int d = 1; d < 16; d <<= 1){
      #pragma unroll
      for (int r = 0; r < 4; ++r) rs[r] += __shfl_xor(rs[r], d);
    }
    #pragma unroll
    for (int r = 0; r < 4; ++r) lreg[r] = lreg[r]*sc[r] + rs[r];
    #pragma unroll
    for (int c2 = 0; c2 < 2; ++c2){
      #pragma unroll
      for (int r = 0; r < 4; ++r) oacc[c2][r] *= sc[r];
    }
    // P -> LDS (wave-local rows; same-wave write->read, lgkmcnt-ordered)
    #pragma unroll
    for (int ct = 0; ct < 4; ++ct){
      #pragma unroll
      for (int r = 0; r < 4; ++r){
        int q = wid*16 + kg*4 + r;
        int k = ct*16 + ml;
        *(unsigned short*)((char*)Psm + q*128 + ((k*2) ^ ((q&7) << 4))) = f2bf(s[ct][r]);
      }
    }
    // O += P V
    int qq = wid*16 + ml;
    #pragma unroll
    for (int ks = 0; ks < 2; ++ks){
      bf16x8 pfr = ldfrag((char*)Psm + qq*128 + ((ks*64 + kg*16) ^ ((qq&7) << 4)));
      #pragma unroll
      for (int c2 = 0; c2 < 2; ++c2){
        int c = c2*16 + ml;
        bf16x8 vfr = ldfrag((char*)&Vsm[cur][0] + c*128 + ((ks*64 + kg*16) ^ ((c&7) << 4)));
        oacc[c2] = mfma16(pfr, vfr, oacc[c2]);
      }
    }
    MEMFENCE();
  }
  // epilogue: partial results (unnormalized O, running m, running l)
  size_t pbase = ((size_t)(ch*8 + h)*NSEQ);
  #pragma unroll
  for (int c2 = 0; c2 < 2; ++c2){
    #pragma unroll
    for (int r = 0; r < 4; ++r){
      int q = qw + kg*4 + r;
      Opart[(pbase + q)*32 + c2*16 + ml] = oacc[c2][r];
    }
  }
  if (ml == 0){
    #pragma unroll
    for (int r = 0; r < 4; ++r){
      int q = qw + kg*4 + r;
      Mpart[pbase + q] = mreg[r];
      Lpart[pbase + q] = lreg[r];
    }
  }
}

// ---------------- kernel 3b: combine kv-chunks + gate ----------------
// grid 256 x 256 threads: thread = (8 n-rows x 32 c). Loops over 8 heads.
__global__ __launch_bounds__(256) void combine_kernel(const float* __restrict__ Opart,
    const float* __restrict__ Mpart, const float* __restrict__ Lpart,
    const unsigned short* __restrict__ Gg, unsigned short* __restrict__ Og){
  int n = blockIdx.x*8 + (threadIdx.x >> 5);
  int c = threadIdx.x & 31;
  #pragma unroll
  for (int h = 0; h < 8; ++h){
    float m0 = Mpart[(size_t)(0*8+h)*NSEQ + n], m1 = Mpart[(size_t)(1*8+h)*NSEQ + n];
    float m2 = Mpart[(size_t)(2*8+h)*NSEQ + n], m3 = Mpart[(size_t)(3*8+h)*NSEQ + n];
    float M = fmaxf(fmaxf(m0, m1), fmaxf(m2, m3));
    float e0 = exp2f((m0-M)*L2E), e1 = exp2f((m1-M)*L2E);
    float e2 = exp2f((m2-M)*L2E), e3 = exp2f((m3-M)*L2E);
    float L = Lpart[(size_t)(0*8+h)*NSEQ + n]*e0 + Lpart[(size_t)(1*8+h)*NSEQ + n]*e1
            + Lpart[(size_t)(2*8+h)*NSEQ + n]*e2 + Lpart[(size_t)(3*8+h)*NSEQ + n]*e3;
    float o = Opart[((size_t)(0*8+h)*NSEQ + n)*32 + c]*e0
            + Opart[((size_t)(1*8+h)*NSEQ + n)*32 + c]*e1
            + Opart[((size_t)(2*8+h)*NSEQ + n)*32 + c]*e2
            + Opart[((size_t)(3*8+h)*NSEQ + n)*32 + c]*e3;
    float g = bf2f(Gg[(size_t)n*256 + h*32 + c]);
    Og[(size_t)n*256 + h*32 + c] = f2bf(o / L * g);
  }
}

// ---------------- kernel 4: output projection ----------------
__global__ __launch_bounds__(256) void oproj_kernel(const unsigned short* __restrict__ Og,
    const unsigned short* __restrict__ Wot, float* __restrict__ out){
  __shared__ unsigned short Asm[64*256];
  __shared__ unsigned short Bsm[64*256];
  int mt = blockIdx.x, nt = blockIdx.y;
  int col0 = nt * 64;
  int tid = threadIdx.x, lane = tid & 63, wid = tid >> 6;
  const char* Ab = (const char*)Og  + (size_t)mt*64*512;
  const char* Bb = (const char*)Wot + (size_t)col0*512;
  char* Asl = (char*)Asm; char* Bsl = (char*)Bsm;
  #pragma unroll
  for (int it = 0; it < 8; ++it){
    int o = it*4096 + wid*1024 + lane*16;
    int row = o >> 9, b = o & 511;
    int sb = (o & ~511) + (b ^ ((row & 15) << 4));
    gload16(Ab + sb, Asl + it*4096 + wid*1024);
    gload16(Bb + sb, Bsl + it*4096 + wid*1024);
  }
  __syncthreads();
  int ml = lane & 15, kg = lane >> 4;
  int m = wid*16 + ml;
  bf16x8 afr[8];
  #pragma unroll
  for (int ks = 0; ks < 8; ++ks)
    afr[ks] = ldfrag(Asl + m*512 + ((ks*64 + kg*16) ^ (ml << 4)));
  f32x4 acc[4];
  #pragma unroll
  for (int ct = 0; ct < 4; ++ct){
    acc[ct] = (f32x4){0.f,0.f,0.f,0.f};
    int oo = ct*16 + ml;
    #pragma unroll
    for (int ks = 0; ks < 8; ++ks){
      bf16x8 bfr = ldfrag(Bsl + oo*512 + ((ks*64 + kg*16) ^ (ml << 4)));
      acc[ct] = mfma16(afr[ks], bfr, acc[ct]);
    }
  }
  #pragma unroll
  for (int ct = 0; ct < 4; ++ct){
    #pragma unroll
    for (int r = 0; r < 4; ++r){
      int mm = mt*64 + wid*16 + kg*4 + r;
      out[(size_t)mm*256 + col0 + ct*16 + ml] = acc[ct][r];
    }
  }
}

extern "C" void kernel_launch(void* const* d_in, const int* in_sizes, int n_in,
                              void* d_out, int out_size, void* d_ws, size_t ws_size,
                              hipStream_t stream) {
  const float* qx   = (const float*)d_in[0];
  const float* kvx  = (const float*)d_in[1];
  const float* bias = (const float*)d_in[2];
  const float* Wq   = (const float*)d_in[3];
  const float* Wk   = (const float*)d_in[4];
  const float* Wv   = (const float*)d_in[5];
  const float* Wg   = (const float*)d_in[6];
  const float* Wo   = (const float*)d_in[7];
  float* out = (float*)d_out;
  char* ws = (char*)d_ws;
  unsigned short* Xbq  = (unsigned short*)(ws);
  unsigned short* Xbkv = (unsigned short*)(ws + (1<<20));
  unsigned short* Wt4  = (unsigned short*)(ws + (2<<20));
  unsigned short* Wot  = (unsigned short*)(ws + (2<<20) + (512<<10));
  unsigned short* Qb   = (unsigned short*)(ws + (3<<20));
  unsigned short* Kb   = (unsigned short*)(ws + (4<<20));
  unsigned short* Vt   = (unsigned short*)(ws + (5<<20));
  unsigned short* Gg   = (unsigned short*)(ws + (6<<20));
  unsigned short* Og   = (unsigned short*)(ws + (7<<20));
  float*          Opart= (float*)(ws + (8<<20));        // 8 MB: [4][8][2048][32]
  float*          Mpart= (float*)(ws + (16<<20));       // 256 KB: [4][8][2048]
  float*          Lpart= (float*)(ws + (17<<20));       // 256 KB

  cvt_kernel<<<592, 256, 0, stream>>>(qx, kvx, Wq, Wk, Wv, Wg, Wo, Xbq, Xbkv, Wt4, Wot);
  dim3 gp(32, 16);
  proj_kernel<<<gp, 256, 0, stream>>>(Xbq, Xbkv, Wt4, Qb, Kb, Vt, Gg);
  attn_kernel<<<1024, 256, 0, stream>>>(Qb, Kb, Vt, bias, Opart, Mpart, Lpart);
  combine_kernel<<<256, 256, 0, stream>>>(Opart, Mpart, Lpart, Gg, Og);
  dim3 go(32, 4);
  oproj_kernel<<<go, 256, 0, stream>>>(Og, Wot, out);
}